// Round 4
// baseline (713.330 us; speedup 1.0000x reference)
//
#include <hip/hip_runtime.h>
#include <hip/hip_bf16.h>

// ---------------- problem constants ----------------
#define BB 8
#define SS 2000
#define IN_CH 120
#define NPTS 10000
#define IC 512
#define CATCH 248
#define CATPAD 256
#define MROWS 16000          // B*S
#define NSLICE 16
#define PTS_PER_SLICE 625

typedef __bf16 bf16x8 __attribute__((ext_vector_type(8)));
typedef float f32x4 __attribute__((ext_vector_type(4)));
typedef unsigned short u16x8 __attribute__((ext_vector_type(8)));

#define DEVI __device__ __forceinline__

DEVI unsigned short f2bf(float f) {
    __hip_bfloat16 h = __float2bfloat16(f);
    return __builtin_bit_cast(unsigned short, h);
}
DEVI float bf2f(unsigned short u) {
    unsigned int x = ((unsigned int)u) << 16;
    return __builtin_bit_cast(float, x);
}
DEVI float leaky(float x) { return x > 0.f ? x : 0.1f * x; }
DEVI unsigned int pk2(float a, float b) {
    return (unsigned int)f2bf(a) | ((unsigned int)f2bf(b) << 16);
}

// slab: [128 rows][512 k] bf16, 1024 B/row, 16B chunks XOR-swizzled by (row&7)
DEVI int slab_addr(int m, int ck) { return m * 1024 + ((ck ^ (m & 7)) << 4); }

// ---------------- workspace layout (bytes) ----------------
static const size_t OFF_FEATS  = 0;            // 8*128 f32
static const size_t OFF_PROJWT = 4096;         // 512*256 bf16
static const size_t OFF_RES0WT = 266240;       // 512*256 bf16
static const size_t OFF_RES1WT = 528384;       // 512*512 bf16
static const size_t OFF_LAYWT  = 1052672;      // 6*512*512 bf16
static const size_t OFF_PART   = 4198400;      // feats partials (16*16*72 f32)
static const size_t OFF_RG     = 12390400;     // r residual [16000][512] bf16 = 16.4MB

// ---------------- weight convert: f32 [L][K][N] -> bf16 [L][N][Kpad] ----
__global__ void wconv_k(const float* __restrict__ src, unsigned short* __restrict__ dst,
                        int K, int Kpad, int N, int total) {
    int idx = blockIdx.x * 256 + threadIdx.x;
    if (idx >= total) return;
    int k = idx % Kpad;
    int rem = idx / Kpad;
    int n = rem % N;
    int l = rem / N;
    float v = (k < K) ? src[((size_t)l * K + k) * N + n] : 0.f;
    dst[idx] = f2bf(v);
}

// ---------------- kernel regression stage 1 ----------------
__global__ __launch_bounds__(256) void feats_part_k(
    const float* __restrict__ gxy, const float* __restrict__ goff,
    const float* __restrict__ bws, const float* __restrict__ g0,
    const float* __restrict__ sloc, float* __restrict__ partial) {
    int bq = blockIdx.x;
    int b = bq >> 1, q = bq & 1;
    float qx = sloc[b * 4 + q * 2 + 0];
    float qy = sloc[b * 4 + q * 2 + 1];
    int i0 = blockIdx.y * PTS_PER_SLICE;
    int iend = i0 + PTS_PER_SLICE;
    float swt = 0.f;
    float sf[64];
#pragma unroll
    for (int c = 0; c < 64; c++) sf[c] = 0.f;
    for (int i = i0 + threadIdx.x; i < iend; i += 256) {
        float gx = gxy[i * 2 + 0] + tanhf(goff[i * 2 + 0]) * 0.1f;
        float gy = gxy[i * 2 + 1] + tanhf(goff[i * 2 + 1]) * 0.1f;
        float bw = fminf(fmaxf(bws[i], 0.1f), 0.5f);
        float dx = qx - gx, dy = qy - gy;
        float w = expf(-(dx * dx + dy * dy) / (bw * bw));
        swt += w;
#pragma unroll
        for (int c = 0; c < 64; c++) sf[c] += w * g0[(size_t)i * 64 + c];
    }
#pragma unroll
    for (int c = 0; c < 64; c++)
        for (int o = 32; o; o >>= 1) sf[c] += __shfl_down(sf[c], o);
    for (int o = 32; o; o >>= 1) swt += __shfl_down(swt, o);
    __shared__ float red[4][65];
    int lane = threadIdx.x & 63, wv = threadIdx.x >> 6;
    if (lane == 0) {
#pragma unroll
        for (int c = 0; c < 64; c++) red[wv][c] = sf[c];
        red[wv][64] = swt;
    }
    __syncthreads();
    size_t base = (size_t)(blockIdx.y * 16 + bq) * 72;
    if (threadIdx.x < 64) {
        int c = threadIdx.x;
        partial[base + c] = red[0][c] + red[1][c] + red[2][c] + red[3][c];
        if (c == 0)
            partial[base + 64] = red[0][64] + red[1][64] + red[2][64] + red[3][64];
    }
}

__global__ __launch_bounds__(128) void feats_reduce_k(
    const float* __restrict__ partial, float* __restrict__ feats) {
    int bq = blockIdx.x;
    __shared__ float s[66];
    int t = threadIdx.x;
    if (t < 65) {
        float acc = 0.f;
        for (int sl = 0; sl < NSLICE; ++sl)
            acc += partial[(size_t)(sl * 16 + bq) * 72 + t];
        s[t] = acc;
    }
    __syncthreads();
    if (t < 64) {
        int b = bq >> 1, q = bq & 1;
        feats[b * 128 + q * 64 + t] = s[t] / s[64];
    }
}

// ---------------- fused MLP chain kernel ----------------
// block = 32 base rows (=128 act rows). slab [128][512] bf16 in LDS holds acts.
// Weights (BT layout [n][Kpad]) streamed to registers per wave, dbuf'd per K-step.
// 8 waves split N: wave wv owns cols wv*64..wv*64+63.

template <int IM>
DEVI void gemm_phase(const char* smem, int arow0, const unsigned short* __restrict__ BT,
                     int Kpad, int nK, int wv, int lane, f32x4 (&acc)[IM][4]) {
    const int fr = lane & 15, c8 = lane >> 4;
#pragma unroll
    for (int i = 0; i < IM; i++)
#pragma unroll
        for (int j = 0; j < 4; j++) acc[i][j] = (f32x4)0.f;

    const unsigned short* Bw = BT + (size_t)(wv * 64 + fr) * Kpad + (size_t)c8 * 8;
    const size_t jstep = (size_t)16 * Kpad;
    uint4 bA[4], bB[4];

#define LOADB(dst, kt)                                                        \
    _Pragma("unroll") for (int j = 0; j < 4; j++)                             \
        dst[j] = *(const uint4*)(Bw + (size_t)j * jstep + (size_t)(kt) * 32);

#define COMPUTE(bb, kt)                                                       \
    {                                                                         \
        bf16x8 av[IM];                                                        \
        _Pragma("unroll") for (int i = 0; i < IM; i++)                        \
            av[i] = *(const bf16x8*)(smem + slab_addr(arow0 + i * 16 + fr, (kt) * 4 + c8)); \
        _Pragma("unroll") for (int i = 0; i < IM; i++)                        \
            _Pragma("unroll") for (int j = 0; j < 4; j++)                     \
                acc[i][j] = __builtin_amdgcn_mfma_f32_16x16x32_bf16(          \
                    av[i], __builtin_bit_cast(bf16x8, bb[j]), acc[i][j], 0, 0, 0); \
    }

    LOADB(bA, 0);
    for (int kt = 0; kt < nK; kt += 2) {
        LOADB(bB, kt + 1);
        COMPUTE(bA, kt);
        if (kt + 2 < nK) LOADB(bA, kt + 2);
        COMPUTE(bB, kt + 1);
    }
#undef LOADB
#undef COMPUTE
}

__global__ void __launch_bounds__(512, 2) fused_k(
    const float* __restrict__ feats, const float* __restrict__ inp,
    const unsigned short* __restrict__ projWT, const float* __restrict__ proj_b,
    const unsigned short* __restrict__ res0WT, const float* __restrict__ res_b0,
    const unsigned short* __restrict__ res1WT, const float* __restrict__ res_b1,
    const unsigned short* __restrict__ layWT, const float* __restrict__ layers_b,
    const float* __restrict__ channels, const float* __restrict__ outW,
    const float* __restrict__ outb, unsigned short* __restrict__ r_g,
    float* __restrict__ out) {
    extern __shared__ __align__(16) char smem[];
    const int tid = threadIdx.x;
    const int lane = tid & 63, wv = tid >> 6;
    const int fr = lane & 15;
    const int hh = lane >> 4;                 // 0..3
    const size_t base0 = (size_t)blockIdx.x * 32;

    // ---- stage my_input -> slab rows 0..31, k 0..255 ----
    {
        int r = tid >> 4;                     // 0..31
        int cp = tid & 15;
        size_t mrow = base0 + r;
        int b = (int)(mrow / SS);
        const float* fb = feats + b * 128;
#pragma unroll
        for (int h = 0; h < 2; ++h) {
            int ck = cp * 2 + h;              // 0..31
            unsigned int w[4];
#pragma unroll
            for (int p = 0; p < 4; ++p) {
                int k = ck * 8 + p * 2;
                float v0 = (k < 128) ? fb[k] : (k < CATCH ? inp[mrow * IN_CH + (k - 128)] : 0.f);
                k++;
                float v1 = (k < 128) ? fb[k] : (k < CATCH ? inp[mrow * IN_CH + (k - 128)] : 0.f);
                w[p] = pk2(v0, v1);
            }
            *(uint4*)(smem + slab_addr(r, ck)) = make_uint4(w[0], w[1], w[2], w[3]);
        }
    }
    __syncthreads();

    f32x4 acc2[2][4];

    // ---- res0: [32][256] @ res0WT -> leaky(+b0) -> slab rows 32..63 ----
    gemm_phase<2>(smem, 0, res0WT, CATPAD, 8, wv, lane, acc2);
#pragma unroll
    for (int i = 0; i < 2; i++) {
#pragma unroll
        for (int j = 0; j < 4; j++) {
            int n = wv * 64 + j * 16 + fr;
            float bn = res_b0[n];
            float v[4];
#pragma unroll
            for (int rg = 0; rg < 4; rg++) v[rg] = leaky(acc2[i][j][rg] + bn);
            unsigned int p01 = pk2(v[0], v[1]), p23 = pk2(v[2], v[3]);
            unsigned int q01 = (unsigned int)__shfl_xor((int)p01, 1);
            unsigned int q23 = (unsigned int)__shfl_xor((int)p23, 1);
            int np = n & ~1;
            int mrow = 32 + i * 16 + hh * 4;
            if (!(fr & 1)) {
                *(unsigned int*)(smem + slab_addr(mrow + 0, np >> 3) + (np & 7) * 2) =
                    (p01 & 0xffffu) | ((q01 & 0xffffu) << 16);
                *(unsigned int*)(smem + slab_addr(mrow + 1, np >> 3) + (np & 7) * 2) =
                    (p01 >> 16) | (q01 & 0xffff0000u);
            } else {
                *(unsigned int*)(smem + slab_addr(mrow + 2, np >> 3) + (np & 7) * 2) =
                    (q23 & 0xffffu) | ((p23 & 0xffffu) << 16);
                *(unsigned int*)(smem + slab_addr(mrow + 3, np >> 3) + (np & 7) * 2) =
                    (q23 >> 16) | (p23 & 0xffff0000u);
            }
        }
    }
    __syncthreads();

    // ---- res1: rows 32..63 @ res1WT + b1 -> r_g (global, bf16) ----
    gemm_phase<2>(smem, 32, res1WT, IC, 16, wv, lane, acc2);
#pragma unroll
    for (int i = 0; i < 2; i++) {
#pragma unroll
        for (int j = 0; j < 4; j++) {
            int n = wv * 64 + j * 16 + fr;
            float bn = res_b1[n];
#pragma unroll
            for (int rg = 0; rg < 4; rg++) {
                int mb = i * 16 + hh * 4 + rg;
                r_g[(base0 + mb) * IC + n] = f2bf(acc2[i][j][rg] + bn);
            }
        }
    }
    // no barrier: r_g visibility covered by later __syncthreads (vmcnt drained)

    // ---- proj: [32][256] @ projWT; expand x4 dirs +ch0, leaky -> slab [128][512] ----
    gemm_phase<2>(smem, 0, projWT, CATPAD, 8, wv, lane, acc2);
    __syncthreads();     // all slab reads (res1 rows 32..63, proj rows 0..31) complete
#pragma unroll
    for (int i = 0; i < 2; i++) {
#pragma unroll
        for (int j = 0; j < 4; j++) {
            int n = wv * 64 + j * 16 + fr;
            float bn = proj_b[n];
            float ch[4];
#pragma unroll
            for (int d = 0; d < 4; d++) ch[d] = channels[d * 512 + n];
            int np = n & ~1;
#pragma unroll
            for (int rg = 0; rg < 4; rg++) {
                int mb = i * 16 + hh * 4 + rg;
                float vb = acc2[i][j][rg] + bn;
                float v[4];
#pragma unroll
                for (int d = 0; d < 4; d++) v[d] = leaky(vb + ch[d]);
                unsigned int p01 = pk2(v[0], v[1]), p23 = pk2(v[2], v[3]);
                unsigned int q01 = (unsigned int)__shfl_xor((int)p01, 1);
                unsigned int q23 = (unsigned int)__shfl_xor((int)p23, 1);
                int m4 = mb * 4;
                if (!(fr & 1)) {
                    *(unsigned int*)(smem + slab_addr(m4 + 0, np >> 3) + (np & 7) * 2) =
                        (p01 & 0xffffu) | ((q01 & 0xffffu) << 16);
                    *(unsigned int*)(smem + slab_addr(m4 + 1, np >> 3) + (np & 7) * 2) =
                        (p01 >> 16) | (q01 & 0xffff0000u);
                } else {
                    *(unsigned int*)(smem + slab_addr(m4 + 2, np >> 3) + (np & 7) * 2) =
                        (q23 & 0xffffu) | ((p23 & 0xffffu) << 16);
                    *(unsigned int*)(smem + slab_addr(m4 + 3, np >> 3) + (np & 7) * 2) =
                        (q23 >> 16) | (p23 & 0xffff0000u);
                }
            }
        }
    }
    __syncthreads();

    // ---- 6 layers: slab @ layWT[l] (+bias+chan[l+1], +r at l==2, leaky except l==5) ----
    f32x4 acc8[8][4];
    for (int l = 0; l < 6; ++l) {
        gemm_phase<8>(smem, 0, layWT + (size_t)l * 262144, IC, 16, wv, lane, acc8);
        __syncthreads();   // all reads done before overwrite
        const float* bias = layers_b + l * 512;
        const float* chan = channels + (l + 1) * 2048;
        const bool use_r = (l == 2);
        const bool do_lk = (l != 5);
#pragma unroll
        for (int i = 0; i < 8; i++) {
#pragma unroll
            for (int j = 0; j < 4; j++) {
                int n = wv * 64 + j * 16 + fr;
                float bn = bias[n];
                float rv = 0.f;
                if (use_r) rv = bf2f(r_g[(base0 + 4 * i + hh) * IC + n]);
                float v[4];
#pragma unroll
                for (int rg = 0; rg < 4; rg++) {
                    float u = acc8[i][j][rg] + bn + chan[rg * 512 + n] + rv;
                    v[rg] = do_lk ? leaky(u) : u;
                }
                unsigned int p01 = pk2(v[0], v[1]), p23 = pk2(v[2], v[3]);
                unsigned int q01 = (unsigned int)__shfl_xor((int)p01, 1);
                unsigned int q23 = (unsigned int)__shfl_xor((int)p23, 1);
                int np = n & ~1;
                int m = i * 16 + hh * 4;
                if (!(fr & 1)) {
                    *(unsigned int*)(smem + slab_addr(m + 0, np >> 3) + (np & 7) * 2) =
                        (p01 & 0xffffu) | ((q01 & 0xffffu) << 16);
                    *(unsigned int*)(smem + slab_addr(m + 1, np >> 3) + (np & 7) * 2) =
                        (p01 >> 16) | (q01 & 0xffff0000u);
                } else {
                    *(unsigned int*)(smem + slab_addr(m + 2, np >> 3) + (np & 7) * 2) =
                        (q23 & 0xffffu) | ((p23 & 0xffffu) << 16);
                    *(unsigned int*)(smem + slab_addr(m + 3, np >> 3) + (np & 7) * 2) =
                        (q23 >> 16) | (p23 & 0xffff0000u);
                }
            }
        }
        __syncthreads();
    }

    // ---- final: out[m][2] = slab_row(m) @ outW + outb ----
    {
        int m = wv * 16 + (lane >> 2);        // 0..127
        int q = lane & 3;
        float s0 = 0.f, s1 = 0.f;
#pragma unroll
        for (int ck = 0; ck < 16; ++ck) {
            u16x8 a = *(const u16x8*)(smem + slab_addr(m, q * 16 + ck));
#pragma unroll
            for (int e = 0; e < 8; ++e) {
                int k = (q * 16 + ck) * 8 + e;
                float av = bf2f(a[e]);
                float2 wp = *(const float2*)&outW[k * 2];
                s0 = fmaf(av, wp.x, s0);
                s1 = fmaf(av, wp.y, s1);
            }
        }
        s0 += __shfl_down(s0, 2); s0 += __shfl_down(s0, 1);
        s1 += __shfl_down(s1, 2); s1 += __shfl_down(s1, 1);
        if (q == 0) {
            size_t gm = (size_t)blockIdx.x * 128 + m;
            out[gm * 2 + 0] = s0 + outb[0];
            out[gm * 2 + 1] = s1 + outb[1];
        }
    }
}

extern "C" void kernel_launch(void* const* d_in, const int* in_sizes, int n_in,
                              void* d_out, int out_size, void* d_ws, size_t ws_size,
                              hipStream_t stream) {
    const float* input_stuff = (const float*)d_in[0];
    const float* sound_loc   = (const float*)d_in[1];
    const float* grid_xy     = (const float*)d_in[2];
    const float* xy_offset   = (const float*)d_in[3];
    const float* bandwidths  = (const float*)d_in[4];
    const float* grid_0      = (const float*)d_in[5];
    const float* proj_W      = (const float*)d_in[6];
    const float* proj_b      = (const float*)d_in[7];
    const float* res_W0      = (const float*)d_in[8];
    const float* res_b0      = (const float*)d_in[9];
    const float* res_W1      = (const float*)d_in[10];
    const float* res_b1      = (const float*)d_in[11];
    const float* layers_W    = (const float*)d_in[12];
    const float* layers_b    = (const float*)d_in[13];
    const float* channels    = (const float*)d_in[14];
    const float* out_W       = (const float*)d_in[15];
    const float* out_b       = (const float*)d_in[16];

    char* ws = (char*)d_ws;
    float* feats            = (float*)(ws + OFF_FEATS);
    unsigned short* projWT  = (unsigned short*)(ws + OFF_PROJWT);
    unsigned short* res0WT  = (unsigned short*)(ws + OFF_RES0WT);
    unsigned short* res1WT  = (unsigned short*)(ws + OFF_RES1WT);
    unsigned short* layWT   = (unsigned short*)(ws + OFF_LAYWT);
    float* partial          = (float*)(ws + OFF_PART);
    unsigned short* r_g     = (unsigned short*)(ws + OFF_RG);

    // weights -> transposed/padded bf16
    wconv_k<<<(512 * 256 + 255) / 256, 256, 0, stream>>>(proj_W, projWT, CATCH, CATPAD, IC, 512 * 256);
    wconv_k<<<(512 * 256 + 255) / 256, 256, 0, stream>>>(res_W0, res0WT, CATCH, CATPAD, IC, 512 * 256);
    wconv_k<<<(512 * 512 + 255) / 256, 256, 0, stream>>>(res_W1, res1WT, IC, IC, IC, 512 * 512);
    wconv_k<<<(6 * 512 * 512 + 255) / 256, 256, 0, stream>>>(layers_W, layWT, IC, IC, IC, 6 * 512 * 512);

    feats_part_k<<<dim3(16, NSLICE), 256, 0, stream>>>(grid_xy, xy_offset, bandwidths, grid_0, sound_loc, partial);
    feats_reduce_k<<<16, 128, 0, stream>>>(partial, feats);

    static int smem_set = 0;
    if (!smem_set) {
        hipFuncSetAttribute((const void*)fused_k,
                            hipFuncAttributeMaxDynamicSharedMemorySize, 131072);
        smem_set = 1;
    }
    fused_k<<<500, 512, 131072, stream>>>(
        feats, input_stuff, projWT, proj_b, res0WT, res_b0, res1WT, res_b1,
        layWT, layers_b, channels, out_W, out_b, r_g, (float*)d_out);
}